// Round 4
// baseline (7616.406 us; speedup 1.0000x reference)
//
#include <hip/hip_runtime.h>
#include <hip/hip_bf16.h>
#include <cstdint>
#include <cstddef>

#define B_ 128
#define T_ 100
#define D_ 2048
#define H_ 1024
#define O_ 20

__device__ inline void f4acc(float4& a, const float4 v) {
    a.x += v.x; a.y += v.y; a.z += v.z; a.w += v.w;
}

// ---------------------------------------------------------------------------
// prep: W2oT[h][o] = Wh2o[o][h]; zero nbr accumulators and bg counters.
// ---------------------------------------------------------------------------
__global__ __launch_bounds__(256) void prep_kernel(const float* __restrict__ Wh2o,
                                                   float* __restrict__ W2oT,
                                                   float* __restrict__ nbr,
                                                   int* __restrict__ g_cnt)
{
    int i = blockIdx.x * 256 + threadIdx.x;
    if (i < H_ * O_) {
        int hh = i / O_;
        int oo = i - hh * O_;
        W2oT[i] = Wh2o[oo * H_ + hh];
    }
    if (i < T_) nbr[i] = 0.0f;
    if (i < 16) g_cnt[i] = 0;
}

// ---------------------------------------------------------------------------
// transpose Wh2h[h][j] -> WT[j][h]
// ---------------------------------------------------------------------------
__global__ __launch_bounds__(256) void transpose_kernel(const float* __restrict__ A,
                                                        float* __restrict__ AT)
{
    __shared__ float tile[32][33];
    int bx = blockIdx.x * 32, by = blockIdx.y * 32;
    int tx = threadIdx.x, ty = threadIdx.y;  // block (32,8)
#pragma unroll
    for (int i = 0; i < 32; i += 8)
        tile[ty + i][tx] = A[(size_t)(by + ty + i) * H_ + bx + tx];
    __syncthreads();
#pragma unroll
    for (int i = 0; i < 32; i += 8)
        AT[(size_t)(bx + ty + i) * H_ + by + tx] = tile[tx][ty + i];
}

// ---------------------------------------------------------------------------
// Xi = X @ Wi2h^T + (bi2h + bh2h).  128x128x16 tile, 256 threads, 8x8 micro.
// ---------------------------------------------------------------------------
__global__ __launch_bounds__(256) void gemm_xi_kernel(
    const float* __restrict__ X,     // [B*T, D]
    const float* __restrict__ W,     // [H, D]
    const float* __restrict__ bi2h,
    const float* __restrict__ bh2h,
    float* __restrict__ Xi)          // [B*T, H]
{
    constexpr int BM = 128, BN = 128, BK = 16;
    __shared__ float As[BK][BM + 4];
    __shared__ float Bs[BK][BN + 4];
    const int tid = threadIdx.x;
    const int m0 = blockIdx.x * BM;
    const int n0 = blockIdx.y * BN;
    const int wave = tid >> 6;
    const int lane = tid & 63;
    const int tm = ((wave >> 1) << 3) | (lane >> 3);   // 0..15
    const int tn = ((wave & 1) << 3) | (lane & 7);     // 0..15
    const int ldr = tid >> 2;          // 0..63
    const int ldc = (tid & 3) << 2;    // 0,4,8,12

    float acc[8][8];
#pragma unroll
    for (int i = 0; i < 8; ++i)
#pragma unroll
        for (int j = 0; j < 8; ++j) acc[i][j] = 0.0f;

    for (int k0 = 0; k0 < D_; k0 += BK) {
#pragma unroll
        for (int p = 0; p < 2; ++p) {
            int r = ldr + p * 64;
            float4 v = *(const float4*)(X + (size_t)(m0 + r) * D_ + k0 + ldc);
            As[ldc + 0][r] = v.x; As[ldc + 1][r] = v.y;
            As[ldc + 2][r] = v.z; As[ldc + 3][r] = v.w;
        }
#pragma unroll
        for (int p = 0; p < 2; ++p) {
            int r = ldr + p * 64;
            float4 v = *(const float4*)(W + (size_t)(n0 + r) * D_ + k0 + ldc);
            Bs[ldc + 0][r] = v.x; Bs[ldc + 1][r] = v.y;
            Bs[ldc + 2][r] = v.z; Bs[ldc + 3][r] = v.w;
        }
        __syncthreads();
#pragma unroll
        for (int k = 0; k < BK; ++k) {
            float4 A0 = *(const float4*)&As[k][tm * 8];
            float4 A1 = *(const float4*)&As[k][tm * 8 + 4];
            float4 B0 = *(const float4*)&Bs[k][tn * 8];
            float4 B1 = *(const float4*)&Bs[k][tn * 8 + 4];
            float a[8] = {A0.x, A0.y, A0.z, A0.w, A1.x, A1.y, A1.z, A1.w};
            float bb[8] = {B0.x, B0.y, B0.z, B0.w, B1.x, B1.y, B1.z, B1.w};
#pragma unroll
            for (int i = 0; i < 8; ++i)
#pragma unroll
                for (int j = 0; j < 8; ++j) acc[i][j] += a[i] * bb[j];
        }
        __syncthreads();
    }

    float bsum[8];
#pragma unroll
    for (int j = 0; j < 8; ++j) {
        int n = n0 + tn * 8 + j;
        bsum[j] = bi2h[n] + bh2h[n];
    }
#pragma unroll
    for (int i = 0; i < 8; ++i) {
        size_t row = (size_t)(m0 + tm * 8 + i);
        float4 o0 = {acc[i][0] + bsum[0], acc[i][1] + bsum[1],
                     acc[i][2] + bsum[2], acc[i][3] + bsum[3]};
        float4 o1 = {acc[i][4] + bsum[4], acc[i][5] + bsum[5],
                     acc[i][6] + bsum[6], acc[i][7] + bsum[7]};
        *(float4*)(Xi + row * H_ + n0 + tn * 8)     = o0;
        *(float4*)(Xi + row * H_ + n0 + tn * 8 + 4) = o1;
    }
}

// ---------------------------------------------------------------------------
// phase2 v4 — DENSE multi-batch recurrence.
// 512 wgs x 320 threads: wg (bg, cg) owns 8 batches (bg*8..) x 32 columns
// (cg*32..). Per step each gather wave reads 256 WT rows once (dense,
// streaming) and applies them to all 8 batches via fmaf(s, w, acc), s in
// {0,1} — fma(0,w,acc)==acc exactly, so numerics == ordered sparse sum.
// Placement: cg = (blk%8)*4 + ((blk>>3)&3) localizes each 128-col slice of
// WT (512 KB) to one XCD under round-robin dispatch (perf heuristic only).
// Per-step bg-wide exchange of 32-bit spike words + o-partials via
// agent-scope atomics, double-buffered; one release-counter per bg.
// Wave 4 of cg==0 wgs computes o-LIF/nbr one step behind (off critical path).
// ---------------------------------------------------------------------------
__global__ __launch_bounds__(320) void phase2_kernel(
    const float* __restrict__ Xi,      // [B*T, H]
    const float* __restrict__ WT,      // [j*H + h]
    const float* __restrict__ W2oT,    // [h*O + o]
    const float* __restrict__ bh2o,
    const float* __restrict__ thr_h_g,
    const float* __restrict__ thr_o_g,
    const float* __restrict__ hm0,
    const float* __restrict__ hs0,
    const float* __restrict__ om0,
    unsigned int* __restrict__ g_mask32,  // [2 buf][128 batch][32 cg]
    float* __restrict__ g_opart,          // [2 buf][128 batch][32 cg][20]
    int* __restrict__ g_cnt,              // [16 bg] monotonic counters
    ulonglong2* __restrict__ spk,         // [B*H]
    float* __restrict__ osum_out,         // [B,O]
    float* __restrict__ nbr_acc)          // [T] pre-zeroed
{
    const int blk = blockIdx.x;
    const int q = blk >> 3;                    // 0..63 (xcd-local slot)
    const int cg = (blk & 7) * 4 + (q & 3);    // 0..31, 4 per XCD
    const int bg = q >> 2;                     // 0..15
    const int b0 = bg * 8;
    const int c0 = cg * 32;
    const int tid = threadIdx.x;
    const int lane = tid & 63;
    const int wv = tid >> 6;                   // 0..4
    const bool docg0 = (cg == 0);

    __shared__ float s_red[1024];              // [wave][b*32+hoff]
    __shared__ unsigned int s_mask32[256];     // [b][w32]  (8 x 32)
    __shared__ float s_om[160], s_osum[160];
    __shared__ float s_bo[O_], s_tho[O_];

    // per-thread LIF state: thread tid<256 owns (b = tid>>5, hoff = tid&31)
    float hm = 0.0f, thr = 1.0f;
    if (tid < 256) {
        int b = tid >> 5, hoff = tid & 31;
        hm = hm0[(size_t)(b0 + b) * H_ + c0 + hoff];
        thr = thr_h_g[c0 + hoff];
    }
    if (tid < 160) {
        s_om[tid] = om0[(b0 + tid / O_) * O_ + tid % O_];
        s_osum[tid] = 0.0f;
    }
    if (tid < O_) { s_bo[tid] = bh2o[tid]; s_tho[tid] = thr_o_g[tid]; }

    // initial masks from hs0 (all 1024 bits of our 8 batches, built locally)
    for (int idx = tid; idx < 256; idx += 320) {
        int b = idx >> 5, w32 = idx & 31;
        const float* base = hs0 + (size_t)(b0 + b) * H_ + w32 * 32;
        unsigned int mw = 0;
#pragma unroll
        for (int k = 0; k < 32; ++k)
            mw |= (base[k] > 0.5f ? 1u : 0u) << k;
        s_mask32[idx] = mw;
    }
    __syncthreads();

    // wave-4 (o-layer) lane->(b,o) assignment, 160 pairs over 3 passes
    int vb[3], vo[3];
#pragma unroll
    for (int p = 0; p < 3; ++p) {
        int idx = p * 64 + lane;
        vb[p] = idx / O_;
        vo[p] = idx - vb[p] * O_;
    }

    unsigned long long bits0 = 0, bits1 = 0;

    for (int t = 0; t <= T_; ++t) {
        const bool full = (t < T_);

        // prefetch Xi(t) early (independent of masks)
        float xi = 0.0f;
        if (full && tid < 256)
            xi = Xi[((size_t)(b0 + (tid >> 5)) * T_ + t) * H_ + c0 + (tid & 31)];

        // wait for all 32 wgs of this bg to have published step t-1
        if (t > 0 && tid == 0) {
            while (__hip_atomic_load(g_cnt + bg, __ATOMIC_ACQUIRE,
                                     __HIP_MEMORY_SCOPE_AGENT) < 32 * t)
                __builtin_amdgcn_s_sleep(2);
        }
        __syncthreads();                       // S1
        if (t > 0 && tid < 256) {
            s_mask32[tid] = __hip_atomic_load(
                g_mask32 + ((t - 1) & 1) * 4096 + (b0 + (tid >> 5)) * 32 + (tid & 31),
                __ATOMIC_RELAXED, __HIP_MEMORY_SCOPE_AGENT);
        }
        __syncthreads();                       // S2

        if (tid < 256) {
            // ---- dense gather: 256 rows for this wave, 8 batches x 32 cols
            if (full) {
                const int gb = lane >> 3;          // batch 0..7
                const int colq = lane & 7;         // float4 column
                const unsigned int* mrow = s_mask32 + gb * 32 + wv * 8;
                const float4* p =
                    (const float4*)(WT + (size_t)(wv * 256) * H_ + c0) + colq;
                float4 a0 = {0, 0, 0, 0}, a1 = {0, 0, 0, 0};
#pragma unroll
                for (int w = 0; w < 8; ++w) {
                    unsigned int mw = mrow[w];
#pragma unroll 4
                    for (int r = 0; r < 32; r += 2) {
                        float s0 = (float)(mw & 1u);
                        float s1 = (float)((mw >> 1) & 1u);
                        mw >>= 2;
                        float4 v0 = p[0];
                        float4 v1 = p[256];
                        a0.x = fmaf(s0, v0.x, a0.x); a0.y = fmaf(s0, v0.y, a0.y);
                        a0.z = fmaf(s0, v0.z, a0.z); a0.w = fmaf(s0, v0.w, a0.w);
                        a1.x = fmaf(s1, v1.x, a1.x); a1.y = fmaf(s1, v1.y, a1.y);
                        a1.z = fmaf(s1, v1.z, a1.z); a1.w = fmaf(s1, v1.w, a1.w);
                        p += 512;
                    }
                }
                f4acc(a0, a1);
                ((float4*)s_red)[wv * 64 + lane] = a0;
            }
        } else if (docg0 && t > 0) {
            // ---- wave 4 of cg==0: o-LIF(t-1) + nbr(t-1), off critical path
            const int bufp = (t - 1) & 1;
            float ospsum = 0.0f;
#pragma unroll
            for (int p = 0; p < 3; ++p) {
                int idx = p * 64 + lane;
                if (idx < 160) {
                    const float* gp =
                        g_opart + bufp * 81920 + ((b0 + vb[p]) * 32) * O_ + vo[p];
                    float oin = s_bo[vo[p]];
#pragma unroll
                    for (int c = 0; c < 32; ++c)
                        oin += __hip_atomic_load(gp + c * O_, __ATOMIC_RELAXED,
                                                 __HIP_MEMORY_SCOPE_AGENT);
                    float om = s_om[idx] + oin;
                    float osp = ((om - s_tho[vo[p]]) > 0.0f) ? 1.0f : 0.0f;
                    if (osp > 0.5f) om = 0.0f;
                    if (om < -s_tho[vo[p]]) om = -s_tho[vo[p]];
                    s_om[idx] = om;
                    s_osum[idx] += osp;
                    ospsum += osp;
                }
            }
            int hid = 0;
#pragma unroll
            for (int k = 0; k < 4; ++k) hid += __popc(s_mask32[lane * 4 + k]);
            float tot = ospsum + (float)hid;
            tot += __shfl_xor(tot, 1);  tot += __shfl_xor(tot, 2);
            tot += __shfl_xor(tot, 4);  tot += __shfl_xor(tot, 8);
            tot += __shfl_xor(tot, 16); tot += __shfl_xor(tot, 32);
            if (lane == 0) atomicAdd(&nbr_acc[t - 1], tot);  // exact ints
        }
        __syncthreads();                       // S3

        if (full && tid < 256) {
            float val = s_red[tid] + s_red[256 + tid] +
                        s_red[512 + tid] + s_red[768 + tid];
            hm += xi + val;
            bool spb = (hm - thr) > 0.0f;      // strict >
            if (spb) hm = 0.0f;
            if (hm < -thr) hm = -thr;
            if (spb) { if (t < 64) bits0 |= 1ull << t; else bits1 |= 1ull << (t - 64); }

            unsigned long long bal = __ballot(spb);
            const int wb = tid >> 6;           // wave: batches 2wb, 2wb+1
            const int buf = t & 1;
            if (lane == 0)
                __hip_atomic_store(g_mask32 + buf * 4096 + (b0 + wb * 2) * 32 + cg,
                                   (unsigned int)bal, __ATOMIC_RELAXED,
                                   __HIP_MEMORY_SCOPE_AGENT);
            if (lane == 32)
                __hip_atomic_store(g_mask32 + buf * 4096 + (b0 + wb * 2 + 1) * 32 + cg,
                                   (unsigned int)(bal >> 32), __ATOMIC_RELAXED,
                                   __HIP_MEMORY_SCOPE_AGENT);
            // own-columns o-partial from this ballot word (ascending bits)
            const int o = lane & 31;
            if (o < O_) {
                unsigned int mm = (lane < 32) ? (unsigned int)bal
                                              : (unsigned int)(bal >> 32);
                const int ob = b0 + wb * 2 + (lane >= 32 ? 1 : 0);
                float op = 0.0f;
                while (mm) {
                    int j = __builtin_ctz(mm);
                    mm &= mm - 1;
                    op += W2oT[(c0 + j) * O_ + o];
                }
                __hip_atomic_store(g_opart + buf * 81920 + (ob * 32 + cg) * O_ + o,
                                   op, __ATOMIC_RELAXED, __HIP_MEMORY_SCOPE_AGENT);
            }
        }
        __syncthreads();                       // S4 (drains vmem incl. wave-4 reads)
        if (full && tid == 0)
            __hip_atomic_fetch_add(g_cnt + bg, 1, __ATOMIC_RELEASE,
                                   __HIP_MEMORY_SCOPE_AGENT);
    }

    if (tid < 256) {
        int b = tid >> 5, hoff = tid & 31;
        ulonglong2 vv; vv.x = bits0; vv.y = bits1;
        spk[(size_t)(b0 + b) * H_ + c0 + hoff] = vv;
    }
    if (docg0 && tid < 160)
        osum_out[(b0 + tid / O_) * O_ + tid % O_] = s_osum[tid];
}

// ---------------------------------------------------------------------------
// sliding-window mean of spike bitmasks
// ---------------------------------------------------------------------------
__global__ __launch_bounds__(256) void filt_kernel(const ulonglong2* __restrict__ spk,
                                                   float* __restrict__ outf)
{
    int i = blockIdx.x * 256 + threadIdx.x;
    ulonglong2 v = spk[i];
    float* o = outf + (size_t)i * 91;
    int s = __popcll(v.x & 0x3FFull);
    o[0] = (float)s * 0.1f;
#pragma unroll 1
    for (int tau = 1; tau <= 90; ++tau) {
        int ta = tau + 9, tsb = tau - 1;
        int add = (ta < 64) ? (int)((v.x >> ta) & 1ull) : (int)((v.y >> (ta - 64)) & 1ull);
        int sub = (tsb < 64) ? (int)((v.x >> tsb) & 1ull) : (int)((v.y >> (tsb - 64)) & 1ull);
        s += add - sub;
        o[tau] = (float)s * 0.1f;
    }
}

// ---------------------------------------------------------------------------
// predictions / loss / nbr scaling
// ---------------------------------------------------------------------------
__global__ __launch_bounds__(256) void final_kernel(const float* __restrict__ osum,
                                                    const int* __restrict__ labels,
                                                    float* __restrict__ dout)
{
    __shared__ float s_loss[B_];
    int tid = threadIdx.x;
    if (tid < B_) {
        int b = tid;
        float v[O_];
#pragma unroll
        for (int o = 0; o < O_; ++o) v[o] = osum[b * O_ + o];
        float mv = v[0];
        int am = 0;
#pragma unroll
        for (int o = 1; o < O_; ++o)
            if (v[o] > mv) { mv = v[o]; am = o; }   // strict >: first max wins
        float se = 0.0f;
#pragma unroll
        for (int o = 0; o < O_; ++o) se += expf(v[o] - mv);
        float lse = mv + logf(se);
        dout[b] = (float)am;
        s_loss[b] = v[labels[b]] - lse;
    }
    if (tid >= 128 && tid < 128 + T_) {
        dout[129 + (tid - 128)] *= (1.0f / (float)B_);
    }
    __syncthreads();
    if (tid == 0) {
        float s = 0.0f;
        for (int b = 0; b < B_; ++b) s += s_loss[b];
        dout[128] = -s / (float)B_;
    }
}

// ---------------------------------------------------------------------------
extern "C" void kernel_launch(void* const* d_in, const int* in_sizes, int n_in,
                              void* d_out, int out_size, void* d_ws, size_t ws_size,
                              hipStream_t stream)
{
    const float* input  = (const float*)d_in[0];
    const int*   labels = (const int*)d_in[1];
    const float* hm0    = (const float*)d_in[2];
    const float* hs0    = (const float*)d_in[3];
    const float* om0    = (const float*)d_in[4];
    const float* Wi2h   = (const float*)d_in[6];
    const float* bi2h   = (const float*)d_in[7];
    const float* Wh2h   = (const float*)d_in[8];
    const float* bh2h   = (const float*)d_in[9];
    const float* Wh2o   = (const float*)d_in[10];
    const float* bh2o   = (const float*)d_in[11];
    const float* thr_h  = (const float*)d_in[12];
    const float* thr_o  = (const float*)d_in[13];

    float* out  = (float*)d_out;
    float* nbr  = out + 129;
    float* filt = out + 229;

    char* ws = (char*)d_ws;
    float*        Xi     = (float*)(ws);                 // 52,428,800
    float*        WT     = (float*)(ws + 52428800);      //  4,194,304
    float*        W2oT   = (float*)(ws + 56623104);      //     81,920
    ulonglong2*   spk    = (ulonglong2*)(ws + 56705024); //  2,097,152
    float*        osum   = (float*)(ws + 58802176);      //     10,240
    unsigned int* g_mask32 = (unsigned int*)(ws + 58812416); // 2*4096*4 = 32,768
    float*        g_opart  = (float*)(ws + 58845184);    // 2*81920*4 = 655,360
    int*          g_cnt    = (int*)(ws + 59500544);      //         64

    prep_kernel<<<80, 256, 0, stream>>>(Wh2o, W2oT, nbr, g_cnt);
    transpose_kernel<<<dim3(32, 32), dim3(32, 8), 0, stream>>>(Wh2h, WT);
    gemm_xi_kernel<<<dim3(100, 8), 256, 0, stream>>>(input, Wi2h, bi2h, bh2h, Xi);
    phase2_kernel<<<512, 320, 0, stream>>>(Xi, WT, W2oT, bh2o, thr_h, thr_o,
                                           hm0, hs0, om0, g_mask32, g_opart, g_cnt,
                                           spk, osum, nbr);
    filt_kernel<<<512, 256, 0, stream>>>(spk, filt);
    final_kernel<<<1, 256, 0, stream>>>(osum, labels, out);
}